// Round 7
// baseline (308928.638 us; speedup 1.0000x reference)
//
#include <hip/hip_runtime.h>
#include <hip/hip_fp16.h>
#include <math.h>

#define GUARD_MAX (1<<18)

typedef float f4 __attribute__((ext_vector_type(4)));
typedef float f2 __attribute__((ext_vector_type(2)));

__device__ __forceinline__ float dot4(const f4 a, const f4 b) {
  return a.x*b.x + a.y*b.y + a.z*b.z + a.w*b.w;
}
__device__ __forceinline__ float sigm(float v) { return 1.f/(1.f + expf(-v)); }

// ---- compiler-tracked device-coherent accessors (no inline-asm loads!) ----
__device__ __forceinline__ float ald(const float* p) {
  unsigned u = __hip_atomic_load((const unsigned*)p, __ATOMIC_RELAXED, __HIP_MEMORY_SCOPE_SYSTEM);
  return __uint_as_float(u);
}
__device__ __forceinline__ int aldi(const int* p) {
  return __hip_atomic_load(p, __ATOMIC_RELAXED, __HIP_MEMORY_SCOPE_SYSTEM);
}
__device__ __forceinline__ f2 ald2(const float* p) {
  unsigned long long u = __hip_atomic_load((const unsigned long long*)p,
                                           __ATOMIC_RELAXED, __HIP_MEMORY_SCOPE_SYSTEM);
  f2 r; r.x = __uint_as_float((unsigned)u); r.y = __uint_as_float((unsigned)(u >> 32));
  return r;
}
__device__ __forceinline__ f4 ald4(const float* p) {
  f2 a = ald2(p), b = ald2(p + 2);
  f4 r; r.x = a.x; r.y = a.y; r.z = b.x; r.w = b.y; return r;
}
__device__ __forceinline__ void ast(float* p, float v) {
  __hip_atomic_store((unsigned*)p, __float_as_uint(v), __ATOMIC_RELAXED, __HIP_MEMORY_SCOPE_SYSTEM);
}
__device__ __forceinline__ void asti(int* p, int v) {
  __hip_atomic_store(p, v, __ATOMIC_RELAXED, __HIP_MEMORY_SCOPE_SYSTEM);
}
__device__ __forceinline__ void ast2(float* p, float a, float b) {
  unsigned long long u = (unsigned long long)__float_as_uint(a)
                       | ((unsigned long long)__float_as_uint(b) << 32);
  __hip_atomic_store((unsigned long long*)p, u, __ATOMIC_RELAXED, __HIP_MEMORY_SCOPE_SYSTEM);
}
// plain cached loads (read-only / cross-kernel data)
__device__ __forceinline__ f4 ld4(const float* p) { return *(const f4*)p; }
__device__ __forceinline__ f4 ld4(const __half* p) {
  uint2 r = *(const uint2*)p;
  __half2 h0 = *reinterpret_cast<__half2*>(&r.x);
  __half2 h1 = *reinterpret_cast<__half2*>(&r.y);
  float2 f0 = __half22float2(h0), f1 = __half22float2(h1);
  f4 o; o.x = f0.x; o.y = f0.y; o.z = f1.x; o.w = f1.y; return o;
}
__device__ __forceinline__ void st1(float* p, float v) { *p = v; }
__device__ __forceinline__ void st1(__half* p, float v) { *p = __float2half(v); }
__device__ __forceinline__ void ld8(const float* p, float* o) {
  *(f4*)&o[0] = *(const f4*)&p[0];
  *(f4*)&o[4] = *(const f4*)&p[4];
}
__device__ __forceinline__ void ld8(const __half* p, float* o) {
  uint4 r = *(const uint4*)p;
  const __half2* h = reinterpret_cast<const __half2*>(&r);
#pragma unroll
  for (int i = 0; i < 4; ++i) { float2 f = __half22float2(h[i]); o[2*i] = f.x; o[2*i+1] = f.y; }
}
__device__ __forceinline__ void atomAddF(float* p, float v) {
  __hip_atomic_fetch_add(p, v, __ATOMIC_RELAXED, __HIP_MEMORY_SCOPE_AGENT);
}
__device__ __forceinline__ void atomAddH2(__half* p, float lo, float hi) {
  unsigned int* u = (unsigned int*)p;
  unsigned int old = __hip_atomic_load(u, __ATOMIC_RELAXED, __HIP_MEMORY_SCOPE_AGENT);
  while (true) {
    __half2 h = *reinterpret_cast<__half2*>(&old);
    float2 f = __half22float2(h);
    __half2 nh = __floats2half2_rn(f.x + lo, f.y + hi);
    unsigned int nv = *reinterpret_cast<unsigned int*>(&nh);
    unsigned int got = atomicCAS(u, old, nv);
    if (got == old) break;
    old = got;
  }
}

// ---------------------------------------------------------------------------
// Flag barrier for LLC-mediated data (all shared data uses SYSTEM-scope
// relaxed atomics => bypass-coherent; no cache fences required).
// arrive: s_waitcnt vmcnt(0) (store-only asm, no output hazards) + sync +
//         relaxed flag store.  wait: wave0 polls packed flags (8B/lane) +
//         compiler memory fence.  Flags packed at stride 1 int.
// ---------------------------------------------------------------------------
__device__ __forceinline__ void bar_wait(const int* flags, int base, int nscan, int tgt) {
  const int tid = threadIdx.x;
  if (tid < 64) {
    int guard = 0;
    for (;;) {
      bool ok = true;
      {
        long long u = __hip_atomic_load((const long long*)(flags + base + tid*2),
                                        __ATOMIC_RELAXED, __HIP_MEMORY_SCOPE_SYSTEM);
        ok = ((int)u >= tgt) && ((int)(u >> 32) >= tgt);
      }
      if (nscan > 128) {
        long long u = __hip_atomic_load((const long long*)(flags + base + 128 + tid*2),
                                        __ATOMIC_RELAXED, __HIP_MEMORY_SCOPE_SYSTEM);
        ok = ok && ((int)u >= tgt) && ((int)(u >> 32) >= tgt);
      }
      if (__all(ok)) break;
      if (++guard > GUARD_MAX) break;   // deadlock parachute
      __builtin_amdgcn_s_sleep(2);
    }
  }
  __syncthreads();
  asm volatile("" ::: "memory");   // compiler fence: no load hoisting above wait
}
__device__ __forceinline__ void bar_arrive(int* flags, int slot, int val) {
  asm volatile("s_waitcnt vmcnt(0)" ::: "memory");  // drain this thread's stores
  __syncthreads();                                   // => all threads drained
  if (threadIdx.x == 0)
    __hip_atomic_store(&flags[slot], val, __ATOMIC_RELAXED, __HIP_MEMORY_SCOPE_SYSTEM);
}

// ---------------------------------------------------------------------------
// persistent bidirectional GRU layer (r4-proven logic; access layer swapped).
// MODE 0: layer0 (x [64][2][1024] -> y0). MODE 1: layer1 (y0 -> Z/U/c via
// fused projections of the previous step's h; +1 epilogue step).
// grid 256 WGs x 512 thr: WG = (dir d, 4-h-slice). Weights LDS-resident.
// h exchange via SYSTEM-scope atomics; per-direction barrier domains.
// ---------------------------------------------------------------------------
template<int MODE, typename YT, typename ZT>
__global__ __launch_bounds__(512, 1)
void k_enc(const float* __restrict__ x0, const YT* __restrict__ yin,
           const float* __restrict__ Wih, const float* __restrict__ Whh,
           const float* __restrict__ bih, const float* __restrict__ bhh,
           YT* __restrict__ yout, float* __restrict__ hbuf,
           float* __restrict__ hfin, int* __restrict__ flags,
           int gen_base, int hfin_base,
           const float* __restrict__ Wq, const float* __restrict__ bq,
           const float* __restrict__ WoutA,
           ZT* __restrict__ Zp, float* __restrict__ Up, float* __restrict__ cp)
{
  constexpr int KTOT = MODE ? 1536 : 512;
  constexpr int NCH  = KTOT / 128;
  constexpr int PADW = KTOT + 4;
  constexpr int SMAX = MODE ? 1025 : 1024;
  __shared__ float Wl[12][PADW];
  __shared__ float Ast[64][132];
  __shared__ float WqL[MODE ? 4 : 1][MODE ? 516 : 4];
  __shared__ float UL[MODE ? 516 : 4];
  __shared__ float bqL[MODE ? 516 : 4];

  const int g   = blockIdx.x;
  const int d   = g >> 7;
  const int sl  = g & 127;
  const int i0  = sl * 4;
  const int tid = threadIdx.x;
  const int w   = tid >> 6, lane = tid & 63;
  const int b   = w*8 + (lane >> 3);
  const int il  = (lane >> 1) & 3;
  const int kh  = lane & 1;
  const int i   = i0 + il;

  for (int u = tid; u < 12*KTOT; u += 512) {
    const int rr = u / KTOT, k = u - rr*KTOT;
    const int R  = (rr >> 2)*512 + i0 + (rr & 3);
    float v;
    if (MODE == 0) v = Whh[(d*1536 + R)*512 + k];
    else v = (k < 512) ? Whh[(d*1536 + R)*512 + k]
                       : Wih[(size_t)(d*1536 + R)*1024 + (k - 512)];
    Wl[rr][k] = v;
  }
  if constexpr (MODE == 1) {
    for (int u = tid; u < 2048; u += 512) {
      const int il2 = u >> 9, k = u & 511;
      WqL[il2][k] = Wq[(d*512 + k)*512 + i0 + il2];
    }
    if (tid < 512) {
      UL[tid]  = WoutA[(size_t)sl*1536 + 512 + d*512 + tid];
      bqL[tid] = bq[d*512 + tid];
    }
  }
  __syncthreads();

  const int Rr = i, Rz = 512 + i, Rn = 1024 + i;
  const float biR = bih[d*1536 + Rr], biZ = bih[d*1536 + Rz], biN = bih[d*1536 + Rn];
  const float bhR = bhh[d*1536 + Rr], bhZ = bhh[d*1536 + Rz], bhN = bhh[d*1536 + Rn];
  float xwR0=0, xwR1=0, xwZ0=0, xwZ1=0, xwN0=0, xwN1=0;
  if (MODE == 0) {
    xwR0 = Wih[(d*1536 + Rr)*2 + 0]; xwR1 = Wih[(d*1536 + Rr)*2 + 1];
    xwZ0 = Wih[(d*1536 + Rz)*2 + 0]; xwZ1 = Wih[(d*1536 + Rz)*2 + 1];
    xwN0 = Wih[(d*1536 + Rn)*2 + 0]; xwN1 = Wih[(d*1536 + Rn)*2 + 1];
  }
  const float* wlR = Wl[0 + il];
  const float* wlZ = Wl[4 + il];
  const float* wlN = Wl[8 + il];
  const float* arow = Ast[b];

  for (int s = 0; s < SMAX; ++s) {
    bar_wait(flags, d*128, 128, gen_base + s);

    const bool doG = (s < 1024);
    const int t = d ? (1023 - s) : s;
    const int cur = s & 1;
    const float* hsrc = hbuf + ((cur*2 + d)*64)*512;
    const int nch = doG ? NCH : 4;

    auto ldchunk = [&](int c, int r) -> f4 {
      const int idx = r*64 + lane, bl = idx >> 5, kq = idx & 31;
      const int bb = w*8 + bl;
      if (MODE == 0 || c < 4) return ald4(hsrc + bb*512 + c*128 + kq*4);  // coherent
      return ld4(yin + ((size_t)bb*1024 + t)*1024 + (c-4)*128 + kq*4);    // cached
    };

    float aR = 0.f, aZ = 0.f, aNh = 0.f, aNi = 0.f, hold = 0.f;
    float zacc = 0.f, uacc = 0.f, cacc = 0.f;
    f4 nb[4];
#pragma unroll
    for (int r = 0; r < 4; ++r) nb[r] = ldchunk(0, r);

    for (int c = 0; c < nch; ++c) {
      // wave-private staging (each wave stages exactly the 8 b-rows it reads)
#pragma unroll
      for (int r = 0; r < 4; ++r) {
        const int idx = r*64 + lane, bl = idx >> 5, kq = idx & 31;
        *(f4*)&Ast[w*8 + bl][kq*4] = nb[r];
      }
      f4 pf[4] = {nb[0], nb[1], nb[2], nb[3]};
      if (c + 1 < nch) {
#pragma unroll
        for (int r = 0; r < 4; ++r) pf[r] = ldchunk(c+1, r);
      }
      const bool is_h = (MODE == 0) || (c < 4);
      const int cb = c*128;
      if (doG) {
        float accN = 0.f;
#pragma unroll
        for (int qq = 0; qq < 16; ++qq) {
          const int kl = (qq*2 + kh)*4;
          const f4 hv = *(const f4*)(arow + kl);
          aR   += dot4(hv, *(const f4*)(wlR + cb + kl));
          aZ   += dot4(hv, *(const f4*)(wlZ + cb + kl));
          accN += dot4(hv, *(const f4*)(wlN + cb + kl));
        }
        if (is_h) aNh += accN; else aNi += accN;
        if (is_h && (i >> 7) == c) hold = arow[i & 127];
      }
      if constexpr (MODE == 1) {
        if (s >= 1 && c < 4) {
          const float* wz = WqL[il];
#pragma unroll
          for (int qq = 0; qq < 16; ++qq) {
            const int kl = (qq*2 + kh)*4;
            zacc += dot4(*(const f4*)(arow + kl), *(const f4*)(wz + cb + kl));
          }
#pragma unroll
          for (int qq = 0; qq < 4; ++qq) {
            const int kl = (qq*8 + il*2 + kh)*4;
            const f4 hv = *(const f4*)(arow + kl);
            uacc += dot4(hv, *(const f4*)(UL + cb + kl));
            if (sl == 0) cacc += dot4(hv, *(const f4*)(bqL + cb + kl));
          }
        }
      }
#pragma unroll
      for (int r = 0; r < 4; ++r) nb[r] = pf[r];
    }

    if (doG) {
      aR  += __shfl_xor(aR, 1);
      aZ  += __shfl_xor(aZ, 1);
      aNh += __shfl_xor(aNh, 1);
      if (MODE) aNi += __shfl_xor(aNi, 1);

      float NI;
      if (MODE == 0) {
        const float xa = x0[(b*2 + 0)*1024 + t];
        const float xb = x0[(b*2 + 1)*1024 + t];
        NI  = xa*xwN0 + xb*xwN1 + biN;
        aR += xa*xwR0 + xb*xwR1;
        aZ += xa*xwZ0 + xb*xwZ1;
      } else {
        NI = aNi + biN;
      }
      const float r_ = sigm(aR + biR + bhR);
      const float z_ = sigm(aZ + biZ + bhZ);
      const float n_ = tanhf(NI + r_*(aNh + bhN));
      const float hn = (1.f - z_)*n_ + z_*hold;

      if (kh == 0) {
        ast(&hbuf[(((cur^1)*2 + d)*64 + b)*512 + i], hn);   // coherent publish
        if constexpr (MODE == 0)
          st1(&yout[((size_t)b*1024 + t)*1024 + d*512 + i], hn);  // cross-kernel
        if (s == 1023) hfin[((hfin_base + d)*64 + b)*512 + i] = hn;
      }
    }
    if constexpr (MODE == 1) {
      if (s >= 1) {
        const int tp = d ? (1024 - s) : (s - 1);
        zacc += __shfl_xor(zacc, 1);
        uacc += __shfl_xor(uacc, 1); uacc += __shfl_xor(uacc, 2); uacc += __shfl_xor(uacc, 4);
        const size_t zbase = ((size_t)b*1024 + tp)*512;
        if constexpr (sizeof(ZT) == 4) {
          if (kh == 0) atomAddF((float*)&Zp[zbase + i], zacc);
        } else {
          const float zhi = __shfl(zacc, lane + 2);   // partner il+1's value
          if (kh == 0 && (il & 1) == 0)
            atomAddH2((__half*)Zp + zbase + i, zacc, zhi);
        }
        if ((lane & 7) == 0) atomAddF(&Up[((size_t)b*1024 + tp)*128 + sl], uacc);
        if (sl == 0) {
          cacc += __shfl_xor(cacc, 1); cacc += __shfl_xor(cacc, 2); cacc += __shfl_xor(cacc, 4);
          if ((lane & 7) == 0) atomAddF(&cp[b*1024 + tp], cacc);
        }
      }
    }
    if (doG) bar_arrive(flags, g, gen_base + s + 1);
  }
}

// ---------------------------------------------------------------------------
// faithful torch h.view(B,-1) projection (verified r3): K = 2048.
// ---------------------------------------------------------------------------
__global__ __launch_bounds__(256, 1)
void k_we2d(const float* __restrict__ hfin, const float* __restrict__ We2d,
            const float* __restrict__ be2d, float* __restrict__ dech,
            int* __restrict__ tok)
{
  const int g = blockIdx.x, tid = threadIdx.x;
  const int r = tid >> 2, jl = tid & 3;
  const int j = g*4 + jl;
  const float* wr = We2d + (size_t)j*2048;
  float acc = 0.f;
  for (int c = 0; c < 2048; c += 4) {
    const int q = r*4 + (c >> 9);
    acc += dot4(*(const f4*)&hfin[((q >> 6)*64 + (q & 63))*512 + (c & 511)],
                *(const f4*)&wr[c]);
  }
  acc += be2d[j];
  const int lp = r >> 5, bb2 = 2*(r & 31) + (j >> 9), hh = j & 511;
  dech[(lp*64 + bb2)*512 + hh] = acc;   // parity 0; kernel-end flush publishes
  if (g == 0 && tid < 64) tok[tid] = 0;
}

// ---------------------------------------------------------------------------
// persistent decoder (r4-proven 4-phase logic; coherent-atomic access layer).
// flags[256..511].
// ---------------------------------------------------------------------------
template<typename ZT>
__global__ __launch_bounds__(256, 1)
void k_dec(const float* __restrict__ emb, const float* __restrict__ dWih,
           const float* __restrict__ dWhh, const float* __restrict__ dbih,
           const float* __restrict__ dbhh, const float* __restrict__ Wout,
           const float* __restrict__ bout, const ZT* __restrict__ Zp,
           const float* __restrict__ Up, const float* __restrict__ cp,
           float* __restrict__ dech, float* __restrict__ scor,
           float* __restrict__ pvU, float* __restrict__ pms,
           int* __restrict__ tok, int* __restrict__ flags,
           float* __restrict__ out)
{
  __shared__ float shmU[4][128];
  __shared__ float wms[8];
  __shared__ float shv[512];
  __shared__ float shl[128];

  const int g = blockIdx.x, tid = threadIdx.x;

  for (int s = 0; s < 32; ++s) {
    const int p = s & 1, pn = p ^ 1;
    const int tb = s*4;

    // ---- phase A: decoder cell, layer 0 ----
    bar_wait(flags, 256, 256, tb);
    if (g < 64) {
      const int b = tid & 63, jj = tid >> 6;
      const int tk = aldi(tok + b);
      const float* xi = emb + (size_t)tk*512;
      const float* hh = dech + ((p*2 + 0)*64 + b)*512;
#pragma unroll
      for (int o = 0; o < 2; ++o) {
        const int j = g*8 + jj + o*4;
        const float* wi = dWih + (size_t)j*512;
        const float* wh = dWhh + (size_t)j*512;
        float acc = dbih[j] + dbhh[j];
        for (int k = 0; k < 512; k += 4) {
          acc += dot4(*(const f4*)&xi[k], *(const f4*)&wi[k]);
          acc += dot4(ald4(&hh[k]), *(const f4*)&wh[k]);
        }
        ast(&dech[((pn*2 + 0)*64 + b)*512 + j], tanhf(acc));
      }
    }
    bar_arrive(flags, 256 + g, tb+1);

    // ---- phase B: decoder cell, layer 1 ----
    bar_wait(flags, 256, 256, tb+1);
    if (g < 64) {
      const int b = tid & 63, jj = tid >> 6;
      const float* xi = dech + ((pn*2 + 0)*64 + b)*512;
      const float* hh = dech + ((p*2 + 1)*64 + b)*512;
#pragma unroll
      for (int o = 0; o < 2; ++o) {
        const int j = g*8 + jj + o*4;
        const float* wi = dWih + (size_t)(512 + j)*512;
        const float* wh = dWhh + (size_t)(512 + j)*512;
        float acc = dbih[512 + j] + dbhh[512 + j];
        for (int k = 0; k < 512; k += 4) {
          acc += dot4(ald4(&xi[k]), *(const f4*)&wi[k]);
          acc += dot4(ald4(&hh[k]), *(const f4*)&wh[k]);
        }
        ast(&dech[((pn*2 + 1)*64 + b)*512 + j], tanhf(acc));
      }
    }
    bar_arrive(flags, 256 + g, tb+2);

    // ---- phase D: attention via Z.vec + c, accumulate U-weighted sums ----
    bar_wait(flags, 256, 256, tb+2);
    {
      const int b = g >> 2, quarter = g & 3;
      const int w = tid >> 6, lane = tid & 63;
      const float* vecb = dech + ((pn*2 + 1)*64 + b)*512;
      float vr[8];
      *(f4*)&vr[0] = ald4(&vecb[lane*8]);
      *(f4*)&vr[4] = ald4(&vecb[lane*8 + 4]);
      float m = -INFINITY, ssum = 0.f, vu0 = 0.f, vu1 = 0.f;
      const int t0 = quarter*256 + w*64;
      for (int tg = 0; tg < 64; tg += 4) {
        float zz[4][8]; float cc[4]; float2 uu[4];
#pragma unroll
        for (int u = 0; u < 4; ++u) {
          const int t = t0 + tg + u;
          ld8(Zp + ((size_t)b*1024 + t)*512 + lane*8, zz[u]);   // cached (RO here)
          uu[u] = *(const float2*)&Up[((size_t)b*1024 + t)*128 + lane*2];
          cc[u] = cp[b*1024 + t];
        }
#pragma unroll
        for (int u = 0; u < 4; ++u) {
          float sc = 0.f;
#pragma unroll
          for (int z = 0; z < 8; ++z) sc += zz[u][z]*vr[z];
#pragma unroll
          for (int off = 1; off < 64; off <<= 1) sc += __shfl_xor(sc, off);
          sc += cc[u];
          if (lane == 0) ast(&scor[b*1024 + t0 + tg + u], sc);
          const float mn = fmaxf(m, sc);
          const float al = expf(m - mn);     // m=-inf first iter -> 0
          const float wt = expf(sc - mn);
          ssum = ssum*al + wt;
          vu0 = vu0*al + wt*uu[u].x;
          vu1 = vu1*al + wt*uu[u].y;
          m = mn;
        }
      }
      shmU[w][lane*2] = vu0; shmU[w][lane*2 + 1] = vu1;
      if (lane == 0) { wms[w] = m; wms[4 + w] = ssum; }
      __syncthreads();
      const float M = fmaxf(fmaxf(wms[0], wms[1]), fmaxf(wms[2], wms[3]));
      const float e0 = expf(wms[0]-M), e1 = expf(wms[1]-M),
                  e2 = expf(wms[2]-M), e3 = expf(wms[3]-M);
      const float S = e0*wms[4] + e1*wms[5] + e2*wms[6] + e3*wms[7];
      if (tid < 128)
        ast(&pvU[(b*4 + quarter)*128 + tid],
            e0*shmU[0][tid] + e1*shmU[1][tid] + e2*shmU[2][tid] + e3*shmU[3][tid]);
      if (tid == 0) ast2(&pms[(b*4+quarter)*2], M, S);
    }
    bar_arrive(flags, 256 + g, tb+3);

    // ---- phase E: combine, logits, argmax, outputs ----
    bar_wait(flags, 256, 256, tb+3);
    if (g < 64) {
      const int b = g;
      f2 ms[4];
#pragma unroll
      for (int c = 0; c < 4; ++c) ms[c] = ald2(&pms[(b*4 + c)*2]);
      const float M = fmaxf(fmaxf(ms[0].x, ms[1].x), fmaxf(ms[2].x, ms[3].x));
      float ee[4]; float S = 0.f;
#pragma unroll
      for (int c = 0; c < 4; ++c) { ee[c] = expf(ms[c].x - M); S += ee[c]*ms[c].y; }
      const float invS = 1.f/S;
      const float* vecb = dech + ((pn*2 + 1)*64 + b)*512;
      {
        f2 v = ald2(&vecb[tid*2]);
        shv[tid*2] = v.x; shv[tid*2+1] = v.y;
      }
      __syncthreads();
      if (tid < 128) {
        const float* wr = Wout + (size_t)tid*1536;
        float acc = bout[tid];
        for (int k = 0; k < 512; k += 4)
          acc += dot4(*(const f4*)&shv[k], *(const f4*)&wr[k]);
        float att = 0.f;
#pragma unroll
        for (int c = 0; c < 4; ++c) att += ee[c]*ald(&pvU[(b*4 + c)*128 + tid]);
        acc += att * invS;
        shl[tid] = acc;
        out[(b*32 + s)*128 + tid] = acc;              // vec_out
      }
      __syncthreads();
      if (tid == 0) {                                  // first-max argmax
        float best = shl[0]; int bi = 0;
        for (int j = 1; j < 128; ++j) if (shl[j] > best) { best = shl[j]; bi = j; }
        asti(&tok[b], bi);
      }
      {
        const f4 scv = ald4(&scor[b*1024 + tid*4]);
        const int t4 = tid*4;
        out[327680 + (b*32 + s)*1024 + t4 + 0] = expf(scv.x - M)*invS;
        out[327680 + (b*32 + s)*1024 + t4 + 1] = expf(scv.y - M)*invS;
        out[327680 + (b*32 + s)*1024 + t4 + 2] = expf(scv.z - M)*invS;
        out[327680 + (b*32 + s)*1024 + t4 + 3] = expf(scv.w - M)*invS;
      }
      if (s == 31) {
        for (int u = tid; u < 1024; u += 256) {
          const int l = u >> 9, h = u & 511;
          out[262144 + (l*64 + b)*512 + h] = ald(&dech[((pn*2 + l)*64 + b)*512 + h]);
        }
      }
    }
    bar_arrive(flags, 256 + g, tb+4);
  }
}

// ---------------------------------------------------------------------------
template<typename YT, typename ZT>
static void run_all(void* const* d_in, void* d_out, void* d_ws, hipStream_t stream) {
  const float* x     = (const float*)d_in[0];
  const float* Wih0  = (const float*)d_in[1];
  const float* Whh0  = (const float*)d_in[2];
  const float* bih0  = (const float*)d_in[3];
  const float* bhh0  = (const float*)d_in[4];
  const float* Wih1  = (const float*)d_in[5];
  const float* Whh1  = (const float*)d_in[6];
  const float* bih1  = (const float*)d_in[7];
  const float* bhh1  = (const float*)d_in[8];
  const float* emb   = (const float*)d_in[9];
  const float* dWih  = (const float*)d_in[10];
  const float* dWhh  = (const float*)d_in[11];
  const float* dbih  = (const float*)d_in[12];
  const float* dbhh  = (const float*)d_in[13];
  const float* Wq    = (const float*)d_in[14];
  const float* bqv   = (const float*)d_in[15];
  const float* We2d  = (const float*)d_in[16];
  const float* be2d  = (const float*)d_in[17];
  const float* Wout  = (const float*)d_in[18];
  const float* boutv = (const float*)d_in[19];

  char* base = (char*)d_ws;
  size_t off = 0;
  auto carve = [&](size_t bytes) { size_t o = off; off += (bytes + 255) & ~(size_t)255; return o; };
  const size_t o_y0   = carve((size_t)67108864 * sizeof(YT));
  const size_t o_Z    = carve((size_t)33554432 * sizeof(ZT));
  const size_t o_U    = carve(33554432);
  const size_t o_c    = carve(262144);
  const size_t o_hbuf = carve(1048576);
  const size_t o_flag = carve(16384);
  const size_t o_hfin = carve(524288);
  const size_t o_dech = carve(524288);
  const size_t o_scor = carve(262144);
  const size_t o_pvU  = carve(131072);
  const size_t o_pms  = carve(2048);
  const size_t o_tok  = carve(256);

  YT*    y0    = (YT*)(base + o_y0);
  ZT*    Zp    = (ZT*)(base + o_Z);
  float* Up    = (float*)(base + o_U);
  float* cp    = (float*)(base + o_c);
  float* hbuf  = (float*)(base + o_hbuf);
  int*   flags = (int*)(base + o_flag);
  float* hfin  = (float*)(base + o_hfin);
  float* dech  = (float*)(base + o_dech);
  float* scor  = (float*)(base + o_scor);
  float* pvU   = (float*)(base + o_pvU);
  float* pms   = (float*)(base + o_pms);
  int*   tok   = (int*)(base + o_tok);

  hipMemsetAsync(base + o_Z, 0, (o_flag + 16384) - o_Z, stream);

  k_enc<0, YT, ZT><<<256, 512, 0, stream>>>(
      x, (const YT*)nullptr, Wih0, Whh0, bih0, bhh0, y0, hbuf, hfin, flags,
      0, 0, nullptr, nullptr, nullptr, (ZT*)nullptr, nullptr, nullptr);
  k_enc<1, YT, ZT><<<256, 512, 0, stream>>>(
      nullptr, y0, Wih1, Whh1, bih1, bhh1, (YT*)nullptr, hbuf + 131072, hfin,
      flags, 1024, 2, Wq, bqv, Wout, Zp, Up, cp);
  k_we2d<<<256, 256, 0, stream>>>(hfin, We2d, be2d, dech, tok);
  k_dec<ZT><<<256, 256, 0, stream>>>(emb, dWih, dWhh, dbih, dbhh, Wout, boutv,
                                     Zp, Up, cp, dech, scor, pvU, pms, tok,
                                     flags, (float*)d_out);
}

extern "C" void kernel_launch(void* const* d_in, const int* in_sizes, int n_in,
                              void* d_out, int out_size, void* d_ws, size_t ws_size,
                              hipStream_t stream) {
  (void)in_sizes; (void)n_in;
  const size_t NEED_A = 438978816;   // y0 f32, Z f32
  const size_t NEED_B = 304761088;   // y0 f16, Z f32
  const size_t NEED_C = 237652224;   // y0 f16, Z f16 (CAS half2 atomics)
  if (ws_size >= NEED_A) {
    run_all<float, float>(d_in, d_out, d_ws, stream);
  } else if (ws_size >= NEED_B) {
    run_all<__half, float>(d_in, d_out, d_ws, stream);
  } else if (ws_size >= NEED_C) {
    run_all<__half, __half>(d_in, d_out, d_ws, stream);
  } else {
    // canary: ws too small for any tier — emit zeros (diagnosable, no fault)
    hipMemsetAsync(d_out, 0, (size_t)out_size * 4, stream);
  }
}

// Round 8
// 308384.351 us; speedup vs baseline: 1.0018x; 1.0018x over previous
//
#include <hip/hip_runtime.h>
#include <hip/hip_fp16.h>
#include <math.h>

#define GUARD_MAX (1<<22)

typedef float f4 __attribute__((ext_vector_type(4)));
typedef float f2 __attribute__((ext_vector_type(2)));

// flag-buffer layout (ints, 128B-separated hot words)
#define CNT_D(d)  ((d)*64)        // enc arrival counter, per direction
#define BC_D(d)   ((d)*64 + 32)   // enc broadcast epoch, per direction
#define CNT_DEC   128
#define BC_DEC    160

__device__ __forceinline__ float dot4(const f4 a, const f4 b) {
  return a.x*b.x + a.y*b.y + a.z*b.z + a.w*b.w;
}
__device__ __forceinline__ float sigm(float v) { return 1.f/(1.f + expf(-v)); }

// ---- compiler-tracked device-coherent accessors (no inline-asm loads) ----
__device__ __forceinline__ float ald(const float* p) {
  unsigned u = __hip_atomic_load((const unsigned*)p, __ATOMIC_RELAXED, __HIP_MEMORY_SCOPE_SYSTEM);
  return __uint_as_float(u);
}
__device__ __forceinline__ int aldi(const int* p) {
  return __hip_atomic_load(p, __ATOMIC_RELAXED, __HIP_MEMORY_SCOPE_SYSTEM);
}
__device__ __forceinline__ f2 ald2(const float* p) {
  unsigned long long u = __hip_atomic_load((const unsigned long long*)p,
                                           __ATOMIC_RELAXED, __HIP_MEMORY_SCOPE_SYSTEM);
  f2 r; r.x = __uint_as_float((unsigned)u); r.y = __uint_as_float((unsigned)(u >> 32));
  return r;
}
__device__ __forceinline__ f4 ald4(const float* p) {
  f2 a = ald2(p), b = ald2(p + 2);
  f4 r; r.x = a.x; r.y = a.y; r.z = b.x; r.w = b.y; return r;
}
__device__ __forceinline__ void ast(float* p, float v) {
  __hip_atomic_store((unsigned*)p, __float_as_uint(v), __ATOMIC_RELAXED, __HIP_MEMORY_SCOPE_SYSTEM);
}
__device__ __forceinline__ void asti(int* p, int v) {
  __hip_atomic_store(p, v, __ATOMIC_RELAXED, __HIP_MEMORY_SCOPE_SYSTEM);
}
__device__ __forceinline__ void ast2(float* p, float a, float b) {
  unsigned long long u = (unsigned long long)__float_as_uint(a)
                       | ((unsigned long long)__float_as_uint(b) << 32);
  __hip_atomic_store((unsigned long long*)p, u, __ATOMIC_RELAXED, __HIP_MEMORY_SCOPE_SYSTEM);
}
// plain cached loads (read-only / cross-kernel data)
__device__ __forceinline__ f4 ld4(const float* p) { return *(const f4*)p; }
__device__ __forceinline__ f4 ld4(const __half* p) {
  uint2 r = *(const uint2*)p;
  __half2 h0 = *reinterpret_cast<__half2*>(&r.x);
  __half2 h1 = *reinterpret_cast<__half2*>(&r.y);
  float2 f0 = __half22float2(h0), f1 = __half22float2(h1);
  f4 o; o.x = f0.x; o.y = f0.y; o.z = f1.x; o.w = f1.y; return o;
}
__device__ __forceinline__ void st1(float* p, float v) { *p = v; }
__device__ __forceinline__ void st1(__half* p, float v) { *p = __float2half(v); }
__device__ __forceinline__ void ld8(const float* p, float* o) {
  *(f4*)&o[0] = *(const f4*)&p[0];
  *(f4*)&o[4] = *(const f4*)&p[4];
}
__device__ __forceinline__ void ld8(const __half* p, float* o) {
  uint4 r = *(const uint4*)p;
  const __half2* h = reinterpret_cast<const __half2*>(&r);
#pragma unroll
  for (int i = 0; i < 4; ++i) { float2 f = __half22float2(h[i]); o[2*i] = f.x; o[2*i+1] = f.y; }
}
__device__ __forceinline__ void atomAddF(float* p, float v) {
  __hip_atomic_fetch_add(p, v, __ATOMIC_RELAXED, __HIP_MEMORY_SCOPE_AGENT);
}
__device__ __forceinline__ void atomAddH2(__half* p, float lo, float hi) {
  unsigned int* u = (unsigned int*)p;
  unsigned int old = __hip_atomic_load(u, __ATOMIC_RELAXED, __HIP_MEMORY_SCOPE_AGENT);
  while (true) {
    __half2 h = *reinterpret_cast<__half2*>(&old);
    float2 f = __half22float2(h);
    __half2 nh = __floats2half2_rn(f.x + lo, f.y + hi);
    unsigned int nv = *reinterpret_cast<unsigned int*>(&nh);
    unsigned int got = atomicCAS(u, old, nv);
    if (got == old) break;
    old = got;
  }
}

// ---------------------------------------------------------------------------
// Counter/broadcast barrier — poll population = 1 lane per WG (was 64).
// arrive: vmcnt(0) drain + __syncthreads + tid0 fetch_add(+1) on the domain
//         counter (agent scope, monotone across kernels); the LAST arriver
//         (old == nwg*tgt-1) publishes epoch tgt to the broadcast flag.
// wait:   tid0 polls the single broadcast flag with s_sleep backoff;
//         __syncthreads releases the block; compiler fence stops hoisting.
// Data visibility: every WG's data stores were vmcnt-acked at the coherence
// point BEFORE its fetch_add executed there; the broadcast store is
// dependency-ordered after the last fetch_add's result. No cache fences
// needed because all shared data moves via scoped (bypass) atomics.
// ---------------------------------------------------------------------------
__device__ __forceinline__ void bar_wait(const int* flags, int bidx, int tgt) {
  if (threadIdx.x == 0) {
    int guard = 0;
    while (__hip_atomic_load(&flags[bidx], __ATOMIC_RELAXED, __HIP_MEMORY_SCOPE_SYSTEM) < tgt) {
      if (++guard > GUARD_MAX) break;   // deadlock parachute
      __builtin_amdgcn_s_sleep(8);
    }
  }
  __syncthreads();
  asm volatile("" ::: "memory");
}
__device__ __forceinline__ void bar_arrive(int* flags, int cidx, int bidx,
                                           int nwg, int tgt) {
  asm volatile("s_waitcnt vmcnt(0)" ::: "memory");  // drain this thread's stores
  __syncthreads();                                   // => whole WG drained
  if (threadIdx.x == 0) {
    const int old = __hip_atomic_fetch_add(&flags[cidx], 1, __ATOMIC_RELAXED,
                                           __HIP_MEMORY_SCOPE_AGENT);
    if (old == nwg*tgt - 1)
      __hip_atomic_store(&flags[bidx], tgt, __ATOMIC_RELAXED, __HIP_MEMORY_SCOPE_SYSTEM);
  }
}

// ---------------------------------------------------------------------------
// persistent bidirectional GRU layer (r7-proven logic; barrier swapped).
// MODE 0: layer0 (x [64][2][1024] -> y0). MODE 1: layer1 (y0 -> Z/U/c via
// fused projections of the previous step's h; +1 epilogue step).
// grid 256 WGs x 512 thr: WG = (dir d, 4-h-slice). Weights LDS-resident.
// h exchange via SYSTEM-scope atomics; per-direction barrier domains.
// ---------------------------------------------------------------------------
template<int MODE, typename YT, typename ZT>
__global__ __launch_bounds__(512, 1)
void k_enc(const float* __restrict__ x0, const YT* __restrict__ yin,
           const float* __restrict__ Wih, const float* __restrict__ Whh,
           const float* __restrict__ bih, const float* __restrict__ bhh,
           YT* __restrict__ yout, float* __restrict__ hbuf,
           float* __restrict__ hfin, int* __restrict__ flags,
           int gen_base, int hfin_base,
           const float* __restrict__ Wq, const float* __restrict__ bq,
           const float* __restrict__ WoutA,
           ZT* __restrict__ Zp, float* __restrict__ Up, float* __restrict__ cp)
{
  constexpr int KTOT = MODE ? 1536 : 512;
  constexpr int NCH  = KTOT / 128;
  constexpr int PADW = KTOT + 4;
  constexpr int SMAX = MODE ? 1025 : 1024;
  __shared__ float Wl[12][PADW];
  __shared__ float Ast[64][132];
  __shared__ float WqL[MODE ? 4 : 1][MODE ? 516 : 4];
  __shared__ float UL[MODE ? 516 : 4];
  __shared__ float bqL[MODE ? 516 : 4];

  const int g   = blockIdx.x;
  const int d   = g >> 7;
  const int sl  = g & 127;
  const int i0  = sl * 4;
  const int tid = threadIdx.x;
  const int w   = tid >> 6, lane = tid & 63;
  const int b   = w*8 + (lane >> 3);
  const int il  = (lane >> 1) & 3;
  const int kh  = lane & 1;
  const int i   = i0 + il;

  for (int u = tid; u < 12*KTOT; u += 512) {
    const int rr = u / KTOT, k = u - rr*KTOT;
    const int R  = (rr >> 2)*512 + i0 + (rr & 3);
    float v;
    if (MODE == 0) v = Whh[(d*1536 + R)*512 + k];
    else v = (k < 512) ? Whh[(d*1536 + R)*512 + k]
                       : Wih[(size_t)(d*1536 + R)*1024 + (k - 512)];
    Wl[rr][k] = v;
  }
  if constexpr (MODE == 1) {
    for (int u = tid; u < 2048; u += 512) {
      const int il2 = u >> 9, k = u & 511;
      WqL[il2][k] = Wq[(d*512 + k)*512 + i0 + il2];
    }
    if (tid < 512) {
      UL[tid]  = WoutA[(size_t)sl*1536 + 512 + d*512 + tid];
      bqL[tid] = bq[d*512 + tid];
    }
  }
  __syncthreads();

  const int Rr = i, Rz = 512 + i, Rn = 1024 + i;
  const float biR = bih[d*1536 + Rr], biZ = bih[d*1536 + Rz], biN = bih[d*1536 + Rn];
  const float bhR = bhh[d*1536 + Rr], bhZ = bhh[d*1536 + Rz], bhN = bhh[d*1536 + Rn];
  float xwR0=0, xwR1=0, xwZ0=0, xwZ1=0, xwN0=0, xwN1=0;
  if (MODE == 0) {
    xwR0 = Wih[(d*1536 + Rr)*2 + 0]; xwR1 = Wih[(d*1536 + Rr)*2 + 1];
    xwZ0 = Wih[(d*1536 + Rz)*2 + 0]; xwZ1 = Wih[(d*1536 + Rz)*2 + 1];
    xwN0 = Wih[(d*1536 + Rn)*2 + 0]; xwN1 = Wih[(d*1536 + Rn)*2 + 1];
  }
  const float* wlR = Wl[0 + il];
  const float* wlZ = Wl[4 + il];
  const float* wlN = Wl[8 + il];
  const float* arow = Ast[b];

  for (int s = 0; s < SMAX; ++s) {
    bar_wait(flags, BC_D(d), gen_base + s);

    const bool doG = (s < 1024);
    const int t = d ? (1023 - s) : s;
    const int cur = s & 1;
    const float* hsrc = hbuf + ((cur*2 + d)*64)*512;
    const int nch = doG ? NCH : 4;

    auto ldchunk = [&](int c, int r) -> f4 {
      const int idx = r*64 + lane, bl = idx >> 5, kq = idx & 31;
      const int bb = w*8 + bl;
      if (MODE == 0 || c < 4) return ald4(hsrc + bb*512 + c*128 + kq*4);  // coherent
      return ld4(yin + ((size_t)bb*1024 + t)*1024 + (c-4)*128 + kq*4);    // cached
    };

    float aR = 0.f, aZ = 0.f, aNh = 0.f, aNi = 0.f, hold = 0.f;
    float zacc = 0.f, uacc = 0.f, cacc = 0.f;
    f4 nb[4];
#pragma unroll
    for (int r = 0; r < 4; ++r) nb[r] = ldchunk(0, r);

    for (int c = 0; c < nch; ++c) {
      // wave-private staging (each wave stages exactly the 8 b-rows it reads)
#pragma unroll
      for (int r = 0; r < 4; ++r) {
        const int idx = r*64 + lane, bl = idx >> 5, kq = idx & 31;
        *(f4*)&Ast[w*8 + bl][kq*4] = nb[r];
      }
      f4 pf[4] = {nb[0], nb[1], nb[2], nb[3]};
      if (c + 1 < nch) {
#pragma unroll
        for (int r = 0; r < 4; ++r) pf[r] = ldchunk(c+1, r);
      }
      const bool is_h = (MODE == 0) || (c < 4);
      const int cb = c*128;
      if (doG) {
        float accN = 0.f;
#pragma unroll
        for (int qq = 0; qq < 16; ++qq) {
          const int kl = (qq*2 + kh)*4;
          const f4 hv = *(const f4*)(arow + kl);
          aR   += dot4(hv, *(const f4*)(wlR + cb + kl));
          aZ   += dot4(hv, *(const f4*)(wlZ + cb + kl));
          accN += dot4(hv, *(const f4*)(wlN + cb + kl));
        }
        if (is_h) aNh += accN; else aNi += accN;
        if (is_h && (i >> 7) == c) hold = arow[i & 127];
      }
      if constexpr (MODE == 1) {
        if (s >= 1 && c < 4) {
          const float* wz = WqL[il];
#pragma unroll
          for (int qq = 0; qq < 16; ++qq) {
            const int kl = (qq*2 + kh)*4;
            zacc += dot4(*(const f4*)(arow + kl), *(const f4*)(wz + cb + kl));
          }
#pragma unroll
          for (int qq = 0; qq < 4; ++qq) {
            const int kl = (qq*8 + il*2 + kh)*4;
            const f4 hv = *(const f4*)(arow + kl);
            uacc += dot4(hv, *(const f4*)(UL + cb + kl));
            if (sl == 0) cacc += dot4(hv, *(const f4*)(bqL + cb + kl));
          }
        }
      }
#pragma unroll
      for (int r = 0; r < 4; ++r) nb[r] = pf[r];
    }

    if (doG) {
      aR  += __shfl_xor(aR, 1);
      aZ  += __shfl_xor(aZ, 1);
      aNh += __shfl_xor(aNh, 1);
      if (MODE) aNi += __shfl_xor(aNi, 1);

      float NI;
      if (MODE == 0) {
        const float xa = x0[(b*2 + 0)*1024 + t];
        const float xb = x0[(b*2 + 1)*1024 + t];
        NI  = xa*xwN0 + xb*xwN1 + biN;
        aR += xa*xwR0 + xb*xwR1;
        aZ += xa*xwZ0 + xb*xwZ1;
      } else {
        NI = aNi + biN;
      }
      const float r_ = sigm(aR + biR + bhR);
      const float z_ = sigm(aZ + biZ + bhZ);
      const float n_ = tanhf(NI + r_*(aNh + bhN));
      const float hn = (1.f - z_)*n_ + z_*hold;

      if (kh == 0) {
        ast(&hbuf[(((cur^1)*2 + d)*64 + b)*512 + i], hn);   // coherent publish
        if constexpr (MODE == 0)
          st1(&yout[((size_t)b*1024 + t)*1024 + d*512 + i], hn);  // cross-kernel
        if (s == 1023) hfin[((hfin_base + d)*64 + b)*512 + i] = hn;
      }
    }
    if constexpr (MODE == 1) {
      if (s >= 1) {
        const int tp = d ? (1024 - s) : (s - 1);
        zacc += __shfl_xor(zacc, 1);
        uacc += __shfl_xor(uacc, 1); uacc += __shfl_xor(uacc, 2); uacc += __shfl_xor(uacc, 4);
        const size_t zbase = ((size_t)b*1024 + tp)*512;
        if constexpr (sizeof(ZT) == 4) {
          if (kh == 0) atomAddF((float*)&Zp[zbase + i], zacc);
        } else {
          const float zhi = __shfl(zacc, lane + 2);   // partner il+1's value
          if (kh == 0 && (il & 1) == 0)
            atomAddH2((__half*)Zp + zbase + i, zacc, zhi);
        }
        if ((lane & 7) == 0) atomAddF(&Up[((size_t)b*1024 + tp)*128 + sl], uacc);
        if (sl == 0) {
          cacc += __shfl_xor(cacc, 1); cacc += __shfl_xor(cacc, 2); cacc += __shfl_xor(cacc, 4);
          if ((lane & 7) == 0) atomAddF(&cp[b*1024 + tp], cacc);
        }
      }
    }
    if (doG) bar_arrive(flags, CNT_D(d), BC_D(d), 128, gen_base + s + 1);
  }
}

// ---------------------------------------------------------------------------
// faithful torch h.view(B,-1) projection (verified r3): K = 2048.
// ---------------------------------------------------------------------------
__global__ __launch_bounds__(256, 1)
void k_we2d(const float* __restrict__ hfin, const float* __restrict__ We2d,
            const float* __restrict__ be2d, float* __restrict__ dech,
            int* __restrict__ tok)
{
  const int g = blockIdx.x, tid = threadIdx.x;
  const int r = tid >> 2, jl = tid & 3;
  const int j = g*4 + jl;
  const float* wr = We2d + (size_t)j*2048;
  float acc = 0.f;
  for (int c = 0; c < 2048; c += 4) {
    const int q = r*4 + (c >> 9);
    acc += dot4(*(const f4*)&hfin[((q >> 6)*64 + (q & 63))*512 + (c & 511)],
                *(const f4*)&wr[c]);
  }
  acc += be2d[j];
  const int lp = r >> 5, bb2 = 2*(r & 31) + (j >> 9), hh = j & 511;
  dech[(lp*64 + bb2)*512 + hh] = acc;   // parity 0; kernel-end flush publishes
  if (g == 0 && tid < 64) tok[tid] = 0;
}

// ---------------------------------------------------------------------------
// persistent decoder (r7-proven 4-phase logic; barrier swapped).
// ---------------------------------------------------------------------------
template<typename ZT>
__global__ __launch_bounds__(256, 1)
void k_dec(const float* __restrict__ emb, const float* __restrict__ dWih,
           const float* __restrict__ dWhh, const float* __restrict__ dbih,
           const float* __restrict__ dbhh, const float* __restrict__ Wout,
           const float* __restrict__ bout, const ZT* __restrict__ Zp,
           const float* __restrict__ Up, const float* __restrict__ cp,
           float* __restrict__ dech, float* __restrict__ scor,
           float* __restrict__ pvU, float* __restrict__ pms,
           int* __restrict__ tok, int* __restrict__ flags,
           float* __restrict__ out)
{
  __shared__ float shmU[4][128];
  __shared__ float wms[8];
  __shared__ float shv[512];
  __shared__ float shl[128];

  const int g = blockIdx.x, tid = threadIdx.x;

  for (int s = 0; s < 32; ++s) {
    const int p = s & 1, pn = p ^ 1;
    const int tb = s*4;

    // ---- phase A: decoder cell, layer 0 ----
    bar_wait(flags, BC_DEC, tb);
    if (g < 64) {
      const int b = tid & 63, jj = tid >> 6;
      const int tk = aldi(tok + b);
      const float* xi = emb + (size_t)tk*512;
      const float* hh = dech + ((p*2 + 0)*64 + b)*512;
#pragma unroll
      for (int o = 0; o < 2; ++o) {
        const int j = g*8 + jj + o*4;
        const float* wi = dWih + (size_t)j*512;
        const float* wh = dWhh + (size_t)j*512;
        float acc = dbih[j] + dbhh[j];
        for (int k = 0; k < 512; k += 4) {
          acc += dot4(*(const f4*)&xi[k], *(const f4*)&wi[k]);
          acc += dot4(ald4(&hh[k]), *(const f4*)&wh[k]);
        }
        ast(&dech[((pn*2 + 0)*64 + b)*512 + j], tanhf(acc));
      }
    }
    bar_arrive(flags, CNT_DEC, BC_DEC, 256, tb+1);

    // ---- phase B: decoder cell, layer 1 ----
    bar_wait(flags, BC_DEC, tb+1);
    if (g < 64) {
      const int b = tid & 63, jj = tid >> 6;
      const float* xi = dech + ((pn*2 + 0)*64 + b)*512;
      const float* hh = dech + ((p*2 + 1)*64 + b)*512;
#pragma unroll
      for (int o = 0; o < 2; ++o) {
        const int j = g*8 + jj + o*4;
        const float* wi = dWih + (size_t)(512 + j)*512;
        const float* wh = dWhh + (size_t)(512 + j)*512;
        float acc = dbih[512 + j] + dbhh[512 + j];
        for (int k = 0; k < 512; k += 4) {
          acc += dot4(ald4(&xi[k]), *(const f4*)&wi[k]);
          acc += dot4(ald4(&hh[k]), *(const f4*)&wh[k]);
        }
        ast(&dech[((pn*2 + 1)*64 + b)*512 + j], tanhf(acc));
      }
    }
    bar_arrive(flags, CNT_DEC, BC_DEC, 256, tb+2);

    // ---- phase D: attention via Z.vec + c, accumulate U-weighted sums ----
    bar_wait(flags, BC_DEC, tb+2);
    {
      const int b = g >> 2, quarter = g & 3;
      const int w = tid >> 6, lane = tid & 63;
      const float* vecb = dech + ((pn*2 + 1)*64 + b)*512;
      float vr[8];
      *(f4*)&vr[0] = ald4(&vecb[lane*8]);
      *(f4*)&vr[4] = ald4(&vecb[lane*8 + 4]);
      float m = -INFINITY, ssum = 0.f, vu0 = 0.f, vu1 = 0.f;
      const int t0 = quarter*256 + w*64;
      for (int tg = 0; tg < 64; tg += 4) {
        float zz[4][8]; float cc[4]; float2 uu[4];
#pragma unroll
        for (int u = 0; u < 4; ++u) {
          const int t = t0 + tg + u;
          ld8(Zp + ((size_t)b*1024 + t)*512 + lane*8, zz[u]);   // cached (RO here)
          uu[u] = *(const float2*)&Up[((size_t)b*1024 + t)*128 + lane*2];
          cc[u] = cp[b*1024 + t];
        }
#pragma unroll
        for (int u = 0; u < 4; ++u) {
          float sc = 0.f;
#pragma unroll
          for (int z = 0; z < 8; ++z) sc += zz[u][z]*vr[z];
#pragma unroll
          for (int off = 1; off < 64; off <<= 1) sc += __shfl_xor(sc, off);
          sc += cc[u];
          if (lane == 0) ast(&scor[b*1024 + t0 + tg + u], sc);
          const float mn = fmaxf(m, sc);
          const float al = expf(m - mn);     // m=-inf first iter -> 0
          const float wt = expf(sc - mn);
          ssum = ssum*al + wt;
          vu0 = vu0*al + wt*uu[u].x;
          vu1 = vu1*al + wt*uu[u].y;
          m = mn;
        }
      }
      shmU[w][lane*2] = vu0; shmU[w][lane*2 + 1] = vu1;
      if (lane == 0) { wms[w] = m; wms[4 + w] = ssum; }
      __syncthreads();
      const float M = fmaxf(fmaxf(wms[0], wms[1]), fmaxf(wms[2], wms[3]));
      const float e0 = expf(wms[0]-M), e1 = expf(wms[1]-M),
                  e2 = expf(wms[2]-M), e3 = expf(wms[3]-M);
      const float S = e0*wms[4] + e1*wms[5] + e2*wms[6] + e3*wms[7];
      if (tid < 128)
        ast(&pvU[(b*4 + quarter)*128 + tid],
            e0*shmU[0][tid] + e1*shmU[1][tid] + e2*shmU[2][tid] + e3*shmU[3][tid]);
      if (tid == 0) ast2(&pms[(b*4+quarter)*2], M, S);
    }
    bar_arrive(flags, CNT_DEC, BC_DEC, 256, tb+3);

    // ---- phase E: combine, logits, argmax, outputs ----
    bar_wait(flags, BC_DEC, tb+3);
    if (g < 64) {
      const int b = g;
      f2 ms[4];
#pragma unroll
      for (int c = 0; c < 4; ++c) ms[c] = ald2(&pms[(b*4 + c)*2]);
      const float M = fmaxf(fmaxf(ms[0].x, ms[1].x), fmaxf(ms[2].x, ms[3].x));
      float ee[4]; float S = 0.f;
#pragma unroll
      for (int c = 0; c < 4; ++c) { ee[c] = expf(ms[c].x - M); S += ee[c]*ms[c].y; }
      const float invS = 1.f/S;
      const float* vecb = dech + ((pn*2 + 1)*64 + b)*512;
      {
        f2 v = ald2(&vecb[tid*2]);
        shv[tid*2] = v.x; shv[tid*2+1] = v.y;
      }
      __syncthreads();
      if (tid < 128) {
        const float* wr = Wout + (size_t)tid*1536;
        float acc = bout[tid];
        for (int k = 0; k < 512; k += 4)
          acc += dot4(*(const f4*)&shv[k], *(const f4*)&wr[k]);
        float att = 0.f;
#pragma unroll
        for (int c = 0; c < 4; ++c) att += ee[c]*ald(&pvU[(b*4 + c)*128 + tid]);
        acc += att * invS;
        shl[tid] = acc;
        out[(b*32 + s)*128 + tid] = acc;              // vec_out
      }
      __syncthreads();
      if (tid == 0) {                                  // first-max argmax
        float best = shl[0]; int bi = 0;
        for (int j = 1; j < 128; ++j) if (shl[j] > best) { best = shl[j]; bi = j; }
        asti(&tok[b], bi);
      }
      {
        const f4 scv = ald4(&scor[b*1024 + tid*4]);
        const int t4 = tid*4;
        out[327680 + (b*32 + s)*1024 + t4 + 0] = expf(scv.x - M)*invS;
        out[327680 + (b*32 + s)*1024 + t4 + 1] = expf(scv.y - M)*invS;
        out[327680 + (b*32 + s)*1024 + t4 + 2] = expf(scv.z - M)*invS;
        out[327680 + (b*32 + s)*1024 + t4 + 3] = expf(scv.w - M)*invS;
      }
      if (s == 31) {
        for (int u = tid; u < 1024; u += 256) {
          const int l = u >> 9, h = u & 511;
          out[262144 + (l*64 + b)*512 + h] = ald(&dech[((pn*2 + l)*64 + b)*512 + h]);
        }
      }
    }
    bar_arrive(flags, CNT_DEC, BC_DEC, 256, tb+4);
  }
}

// ---------------------------------------------------------------------------
template<typename YT, typename ZT>
static void run_all(void* const* d_in, void* d_out, void* d_ws, hipStream_t stream) {
  const float* x     = (const float*)d_in[0];
  const float* Wih0  = (const float*)d_in[1];
  const float* Whh0  = (const float*)d_in[2];
  const float* bih0  = (const float*)d_in[3];
  const float* bhh0  = (const float*)d_in[4];
  const float* Wih1  = (const float*)d_in[5];
  const float* Whh1  = (const float*)d_in[6];
  const float* bih1  = (const float*)d_in[7];
  const float* bhh1  = (const float*)d_in[8];
  const float* emb   = (const float*)d_in[9];
  const float* dWih  = (const float*)d_in[10];
  const float* dWhh  = (const float*)d_in[11];
  const float* dbih  = (const float*)d_in[12];
  const float* dbhh  = (const float*)d_in[13];
  const float* Wq    = (const float*)d_in[14];
  const float* bqv   = (const float*)d_in[15];
  const float* We2d  = (const float*)d_in[16];
  const float* be2d  = (const float*)d_in[17];
  const float* Wout  = (const float*)d_in[18];
  const float* boutv = (const float*)d_in[19];

  char* base = (char*)d_ws;
  size_t off = 0;
  auto carve = [&](size_t bytes) { size_t o = off; off += (bytes + 255) & ~(size_t)255; return o; };
  const size_t o_y0   = carve((size_t)67108864 * sizeof(YT));
  const size_t o_Z    = carve((size_t)33554432 * sizeof(ZT));
  const size_t o_U    = carve(33554432);
  const size_t o_c    = carve(262144);
  const size_t o_hbuf = carve(1048576);
  const size_t o_flag = carve(16384);
  const size_t o_hfin = carve(524288);
  const size_t o_dech = carve(524288);
  const size_t o_scor = carve(262144);
  const size_t o_pvU  = carve(131072);
  const size_t o_pms  = carve(2048);
  const size_t o_tok  = carve(256);

  YT*    y0    = (YT*)(base + o_y0);
  ZT*    Zp    = (ZT*)(base + o_Z);
  float* Up    = (float*)(base + o_U);
  float* cp    = (float*)(base + o_c);
  float* hbuf  = (float*)(base + o_hbuf);
  int*   flags = (int*)(base + o_flag);
  float* hfin  = (float*)(base + o_hfin);
  float* dech  = (float*)(base + o_dech);
  float* scor  = (float*)(base + o_scor);
  float* pvU   = (float*)(base + o_pvU);
  float* pms   = (float*)(base + o_pms);
  int*   tok   = (int*)(base + o_tok);

  hipMemsetAsync(base + o_Z, 0, (o_flag + 16384) - o_Z, stream);

  k_enc<0, YT, ZT><<<256, 512, 0, stream>>>(
      x, (const YT*)nullptr, Wih0, Whh0, bih0, bhh0, y0, hbuf, hfin, flags,
      0, 0, nullptr, nullptr, nullptr, (ZT*)nullptr, nullptr, nullptr);
  k_enc<1, YT, ZT><<<256, 512, 0, stream>>>(
      nullptr, y0, Wih1, Whh1, bih1, bhh1, (YT*)nullptr, hbuf + 131072, hfin,
      flags, 1024, 2, Wq, bqv, Wout, Zp, Up, cp);
  k_we2d<<<256, 256, 0, stream>>>(hfin, We2d, be2d, dech, tok);
  k_dec<ZT><<<256, 256, 0, stream>>>(emb, dWih, dWhh, dbih, dbhh, Wout, boutv,
                                     Zp, Up, cp, dech, scor, pvU, pms, tok,
                                     flags, (float*)d_out);
}

extern "C" void kernel_launch(void* const* d_in, const int* in_sizes, int n_in,
                              void* d_out, int out_size, void* d_ws, size_t ws_size,
                              hipStream_t stream) {
  (void)in_sizes; (void)n_in;
  const size_t NEED_A = 438978816;   // y0 f32, Z f32
  const size_t NEED_B = 304761088;   // y0 f16, Z f32
  const size_t NEED_C = 237652224;   // y0 f16, Z f16 (CAS half2 atomics)
  if (ws_size >= NEED_A) {
    run_all<float, float>(d_in, d_out, d_ws, stream);
  } else if (ws_size >= NEED_B) {
    run_all<__half, float>(d_in, d_out, d_ws, stream);
  } else if (ws_size >= NEED_C) {
    run_all<__half, __half>(d_in, d_out, d_ws, stream);
  } else {
    // canary: ws too small for any tier — emit zeros (diagnosable, no fault)
    hipMemsetAsync(d_out, 0, (size_t)out_size * 4, stream);
  }
}

// Round 10
// 96779.742 us; speedup vs baseline: 3.1921x; 3.1865x over previous
//
#include <hip/hip_runtime.h>
#include <math.h>

typedef float    f4 __attribute__((ext_vector_type(4)));
typedef float    f2 __attribute__((ext_vector_type(2)));
typedef _Float16 h2 __attribute__((ext_vector_type(2)));

#define GUARD_MAX (1<<22)
#define CNT_DEC   128
#define BC_DEC    160

__device__ __forceinline__ float dot4(const f4 a, const f4 b) {
  return a.x*b.x + a.y*b.y + a.z*b.z + a.w*b.w;
}
__device__ __forceinline__ float sigm(float v) { return 1.f/(1.f + expf(-v)); }

__device__ __forceinline__ float fdot2f(h2 a, h2 b, float c) {
#if __has_builtin(__builtin_amdgcn_fdot2)
  return __builtin_amdgcn_fdot2(a, b, c, false);
#else
  return c + (float)a.x*(float)b.x + (float)a.y*(float)b.y;
#endif
}

// ---- coherent accessors (decoder only; proven r7/r8) ----
__device__ __forceinline__ float ald(const float* p) {
  unsigned u = __hip_atomic_load((const unsigned*)p, __ATOMIC_RELAXED, __HIP_MEMORY_SCOPE_SYSTEM);
  return __uint_as_float(u);
}
__device__ __forceinline__ int aldi(const int* p) {
  return __hip_atomic_load(p, __ATOMIC_RELAXED, __HIP_MEMORY_SCOPE_SYSTEM);
}
__device__ __forceinline__ f2 ald2(const float* p) {
  unsigned long long u = __hip_atomic_load((const unsigned long long*)p,
                                           __ATOMIC_RELAXED, __HIP_MEMORY_SCOPE_SYSTEM);
  f2 r; r.x = __uint_as_float((unsigned)u); r.y = __uint_as_float((unsigned)(u >> 32));
  return r;
}
__device__ __forceinline__ f4 ald4(const float* p) {
  f2 a = ald2(p), b = ald2(p + 2);
  f4 r; r.x = a.x; r.y = a.y; r.z = b.x; r.w = b.y; return r;
}
__device__ __forceinline__ void ast(float* p, float v) {
  __hip_atomic_store((unsigned*)p, __float_as_uint(v), __ATOMIC_RELAXED, __HIP_MEMORY_SCOPE_SYSTEM);
}
__device__ __forceinline__ void asti(int* p, int v) {
  __hip_atomic_store(p, v, __ATOMIC_RELAXED, __HIP_MEMORY_SCOPE_SYSTEM);
}
__device__ __forceinline__ void ast2(float* p, float a, float b) {
  unsigned long long u = (unsigned long long)__float_as_uint(a)
                       | ((unsigned long long)__float_as_uint(b) << 32);
  __hip_atomic_store((unsigned long long*)p, u, __ATOMIC_RELAXED, __HIP_MEMORY_SCOPE_SYSTEM);
}
__device__ __forceinline__ void ld8(const float* p, float* o) {
  *(f4*)&o[0] = *(const f4*)&p[0];
  *(f4*)&o[4] = *(const f4*)&p[4];
}
__device__ __forceinline__ void ld8(const _Float16* p, float* o) {
  uint4 r = *(const uint4*)p;
  const h2* hh = (const h2*)&r;
#pragma unroll
  for (int i = 0; i < 4; ++i) { o[2*i] = (float)hh[i].x; o[2*i+1] = (float)hh[i].y; }
}
__device__ __forceinline__ void atomAddF(float* p, float v) {
  __hip_atomic_fetch_add(p, v, __ATOMIC_RELAXED, __HIP_MEMORY_SCOPE_AGENT);
}
__device__ __forceinline__ void atomAddH2(_Float16* p, float lo, float hi) {
  unsigned* u = (unsigned*)p;                       // 4B-aligned (even index)
  unsigned old = __hip_atomic_load(u, __ATOMIC_RELAXED, __HIP_MEMORY_SCOPE_AGENT);
  for (;;) {
    h2 c = *(h2*)&old;
    h2 n; n.x = (_Float16)((float)c.x + lo); n.y = (_Float16)((float)c.y + hi);
    unsigned nv = *(unsigned*)&n;
    unsigned got = atomicCAS(u, old, nv);
    if (got == old) break;
    old = got;
  }
}

// ---- decoder barrier (r8-proven) ----
__device__ __forceinline__ void bar_wait(const int* flags, int bidx, int tgt) {
  if (threadIdx.x == 0) {
    int guard = 0;
    while (__hip_atomic_load(&flags[bidx], __ATOMIC_RELAXED, __HIP_MEMORY_SCOPE_SYSTEM) < tgt) {
      if (++guard > GUARD_MAX) break;
      __builtin_amdgcn_s_sleep(8);
    }
  }
  __syncthreads();
  asm volatile("" ::: "memory");
}
__device__ __forceinline__ void bar_arrive(int* flags, int cidx, int bidx,
                                           int nwg, int tgt) {
  asm volatile("s_waitcnt vmcnt(0)" ::: "memory");
  __syncthreads();
  if (threadIdx.x == 0) {
    const int old = __hip_atomic_fetch_add(&flags[cidx], 1, __ATOMIC_RELAXED,
                                           __HIP_MEMORY_SCOPE_AGENT);
    if (old == nwg*tgt - 1)
      __hip_atomic_store(&flags[bidx], tgt, __ATOMIC_RELAXED, __HIP_MEMORY_SCOPE_SYSTEM);
  }
}

// ---------------------------------------------------------------------------
// fp16 k-pair packer (r9-verified layout):
// dst[((dd*KK+kk)*R+row)*2+p] = src[dd*dStep + row*rowStride + (2kk+p)*kStride + dOff0]
// ---------------------------------------------------------------------------
__global__ void k_pack(const float* __restrict__ src, _Float16* __restrict__ dst,
                       int R, int KK, int rowStride, int kStride, int dOff0, int dStep) {
  const int total = 2*KK*R*2;
  for (int idx = blockIdx.x*256 + threadIdx.x; idx < total; idx += gridDim.x*256) {
    const int p   = idx & 1;
    const int row = (idx >> 1) % R;
    const int kk  = ((idx >> 1) / R) % KK;
    const int dd  = (idx >> 1) / (R*KK);
    dst[idx] = (_Float16)src[(size_t)dd*dStep + (size_t)row*rowStride
                             + (size_t)(2*kk + p)*kStride + dOff0];
  }
}
// f32 k-major f4 packer for Whh: dst_f4[(dd*128+kk)*1536+row] = Whh[dd][row][4kk..4kk+3]
__global__ void k_packf(const float* __restrict__ src, float* __restrict__ dst) {
  const int total = 2*128*1536;   // f4 count
  for (int idx = blockIdx.x*256 + threadIdx.x; idx < total; idx += gridDim.x*256) {
    const int row = idx % 1536;
    const int kk  = (idx / 1536) & 127;
    const int dd  = idx / (1536*128);
    const float* s = src + (size_t)dd*786432 + (size_t)row*512 + kk*4;
    f4 v; v.x = s[0]; v.y = s[1]; v.z = s[2]; v.w = s[3];
    *(f4*)&dst[(size_t)idx*4] = v;
  }
}

// ---------------------------------------------------------------------------
// Batch-parallel persistent GRU layer — ZERO inter-WG communication.
// WG = (2-batch group, direction via XCD-affinity map). 512 thr; thread j owns
// h-index j (gate rows j, 512+j, 1024+j). h fp32 in LDS (double-buffered),
// Whh fp32 k-major f4 (L2-resident per direction). Input gates windowed (T=8):
// y0 fp16 staged to LDS, Wih1 fp16 k-pair streamed once/window, gi in regs.
// MODE 1 adds windowed Z/U/c projections from fp16 h-window (CAS atomics).
// ---------------------------------------------------------------------------
template<int MODE>
__global__ __launch_bounds__(512, 1)
void k_gru(const float* __restrict__ x0, const _Float16* __restrict__ yin,
           _Float16* __restrict__ yout,
           const float* __restrict__ WhhP, const _Float16* __restrict__ WixP,
           const float* __restrict__ Wih0,
           const float* __restrict__ bih, const float* __restrict__ bhh,
           float* __restrict__ hfin, int hfin_base,
           const _Float16* __restrict__ Wqp, const _Float16* __restrict__ Upk,
           const _Float16* __restrict__ bqp,
           _Float16* __restrict__ Zp, _Float16* __restrict__ Up,
           float* __restrict__ cp)
{
  const int g    = blockIdx.x;
  const int xcd  = g & 7;
  const int d    = (xcd < 4) ? 0 : 1;            // direction per XCD half
  const int idxd = (g >> 3)*4 + (xcd & 3);       // 0..31 within direction
  const int b0   = idxd * 2;                      // NB = 2
  const int j    = threadIdx.x;

  __shared__ float    hF[2][2][512];              // [buf][b][k] fp32
  __shared__ h2       xW[MODE ? 8 : 1][MODE ? 2 : 1][MODE ? 512 : 1];
  __shared__ _Float16 hW[MODE ? 8 : 1][MODE ? 2 : 1][MODE ? 512 : 1];

  hF[0][0][j] = 0.f; hF[0][1][j] = 0.f;

  const float biR = bih[d*1536 + j],        bhR = bhh[d*1536 + j];
  const float biZ = bih[d*1536 + 512 + j],  bhZ = bhh[d*1536 + 512 + j];
  const float biN = bih[d*1536 + 1024 + j], bhN = bhh[d*1536 + 1024 + j];
  float xwR0=0,xwR1=0,xwZ0=0,xwZ1=0,xwN0=0,xwN1=0;
  if (MODE == 0) {
    xwR0 = Wih0[(d*1536 + j)*2 + 0];        xwR1 = Wih0[(d*1536 + j)*2 + 1];
    xwZ0 = Wih0[(d*1536 + 512 + j)*2 + 0];  xwZ1 = Wih0[(d*1536 + 512 + j)*2 + 1];
    xwN0 = Wih0[(d*1536 + 1024 + j)*2 + 0]; xwN1 = Wih0[(d*1536 + 1024 + j)*2 + 1];
  }
  const f4* wh = (const f4*)WhhP + (size_t)d*196608;            // [128][1536]
  const h2* wx = MODE ? (const h2*)WixP + (size_t)d*786432 : (const h2*)nullptr;
  const h2* wq = MODE ? (const h2*)Wqp + d*131072 : (const h2*)nullptr;
  const h2* wu = MODE ? (const h2*)Upk + d*32768  : (const h2*)nullptr;
  const h2* wb = MODE ? (const h2*)bqp + d*256    : (const h2*)nullptr;
  __syncthreads();

  int cur = 0;
  for (int s8 = 0; s8 < 128; ++s8) {
    float gi[8][2][3];
    if constexpr (MODE == 1) {
      // stage y0 window: 8 t x 2 b x 512 pairs = 2048 uint4
      for (int n = j; n < 2048; n += 512) {
        const int tw = n >> 8, b = (n >> 7) & 1, q = n & 127;
        const int t = d ? 1023 - (s8*8 + tw) : (s8*8 + tw);
        ((uint4*)&xW[tw][b][0])[q] =
            ((const uint4*)(yin + ((size_t)(b0+b)*1024 + t)*1024))[q];
      }
      __syncthreads();
#pragma unroll
      for (int tw = 0; tw < 8; ++tw)
#pragma unroll
        for (int b = 0; b < 2; ++b) { gi[tw][b][0]=0.f; gi[tw][b][1]=0.f; gi[tw][b][2]=0.f; }
      for (int kk = 0; kk < 512; ++kk) {          // input GEMM, K=1024
        const h2 wr = wx[kk*1536 + j];
        const h2 wz = wx[kk*1536 + 512 + j];
        const h2 wn = wx[kk*1536 + 1024 + j];
#pragma unroll
        for (int tw = 0; tw < 8; ++tw)
#pragma unroll
          for (int b = 0; b < 2; ++b) {
            const h2 xv = xW[tw][b][kk];
            gi[tw][b][0] = fdot2f(wr, xv, gi[tw][b][0]);
            gi[tw][b][1] = fdot2f(wz, xv, gi[tw][b][1]);
            gi[tw][b][2] = fdot2f(wn, xv, gi[tw][b][2]);
          }
      }
    }

    // ---- 8 recurrence steps (fp32) ----
#pragma unroll
    for (int tw = 0; tw < 8; ++tw) {
      const int s = s8*8 + tw;
      const int t = d ? 1023 - s : s;
      float aR[2], aZ[2], aNh[2], NI[2];
      if constexpr (MODE == 1) {
#pragma unroll
        for (int b = 0; b < 2; ++b) {
          aR[b] = gi[tw][b][0]; aZ[b] = gi[tw][b][1]; NI[b] = gi[tw][b][2] + biN;
          aNh[b] = 0.f;
        }
      } else {
#pragma unroll
        for (int b = 0; b < 2; ++b) {
          const float xa = x0[((b0+b)*2 + 0)*1024 + t];
          const float xb = x0[((b0+b)*2 + 1)*1024 + t];
          aR[b] = xa*xwR0 + xb*xwR1;
          aZ[b] = xa*xwZ0 + xb*xwZ1;
          NI[b] = xa*xwN0 + xb*xwN1 + biN;
          aNh[b] = 0.f;
        }
      }
#pragma unroll 2
      for (int kk = 0; kk < 128; ++kk) {          // Whh fp32, K=512
        const f4 w4r = wh[kk*1536 + j];
        const f4 w4z = wh[kk*1536 + 512 + j];
        const f4 w4n = wh[kk*1536 + 1024 + j];
#pragma unroll
        for (int b = 0; b < 2; ++b) {
          const f4 hv = *(const f4*)&hF[cur][b][kk*4];
          aR[b]  += dot4(w4r, hv);
          aZ[b]  += dot4(w4z, hv);
          aNh[b] += dot4(w4n, hv);
        }
      }
#pragma unroll
      for (int b = 0; b < 2; ++b) {
        const float r_ = sigm(aR[b] + biR + bhR);
        const float z_ = sigm(aZ[b] + biZ + bhZ);
        const float n_ = tanhf(NI[b] + r_*(aNh[b] + bhN));
        const float hn = (1.f - z_)*n_ + z_*hF[cur][b][j];
        hF[cur^1][b][j] = hn;
        if constexpr (MODE == 1) hW[tw][b][j] = (_Float16)hn;
        if constexpr (MODE == 0)
          yout[((size_t)(b0+b)*1024 + t)*1024 + d*512 + j] = (_Float16)hn;
        if (s == 1023) hfin[((hfin_base + d)*64 + (b0+b))*512 + j] = hn;
      }
      cur ^= 1;
      __syncthreads();
    }

    // ---- windowed projections (MODE 1): Z, U, c from fp16 h-window ----
    if constexpr (MODE == 1) {
      float za[8][2];
#pragma unroll
      for (int tw = 0; tw < 8; ++tw) { za[tw][0] = 0.f; za[tw][1] = 0.f; }
      for (int kk = 0; kk < 256; ++kk) {
        const h2 wv = wq[kk*512 + j];
#pragma unroll
        for (int tw = 0; tw < 8; ++tw)
#pragma unroll
          for (int b = 0; b < 2; ++b)
            za[tw][b] = fdot2f(wv, ((const h2*)&hW[tw][b][0])[kk], za[tw][b]);
      }
#pragma unroll
      for (int tw = 0; tw < 8; ++tw) {
        const int t = d ? 1023 - (s8*8 + tw) : (s8*8 + tw);
#pragma unroll
        for (int b = 0; b < 2; ++b) {
          const float zhi = __shfl_down(za[tw][b], 1);
          if (!(j & 1))
            atomAddH2(&Zp[((size_t)(b0+b)*1024 + t)*512 + j], za[tw][b], zhi);
        }
      }
      if (j < 128) {                               // U columns
        float ua[8][2];
#pragma unroll
        for (int tw = 0; tw < 8; ++tw) { ua[tw][0] = 0.f; ua[tw][1] = 0.f; }
        for (int kk = 0; kk < 256; ++kk) {
          const h2 wv = wu[kk*128 + j];
#pragma unroll
          for (int tw = 0; tw < 8; ++tw)
#pragma unroll
            for (int b = 0; b < 2; ++b)
              ua[tw][b] = fdot2f(wv, ((const h2*)&hW[tw][b][0])[kk], ua[tw][b]);
        }
#pragma unroll
        for (int tw = 0; tw < 8; ++tw) {
          const int t = d ? 1023 - (s8*8 + tw) : (s8*8 + tw);
#pragma unroll
          for (int b = 0; b < 2; ++b) {
            const float uhi = __shfl_down(ua[tw][b], 1);
            if (!(j & 1))
              atomAddH2(&Up[((size_t)(b0+b)*1024 + t)*128 + j], ua[tw][b], uhi);
          }
        }
      } else if (j < 192) {                        // c (wave 2, lanes 0..63)
        const int l = j - 128;
        float ca[8][2];
#pragma unroll
        for (int tw = 0; tw < 8; ++tw) { ca[tw][0] = 0.f; ca[tw][1] = 0.f; }
#pragma unroll
        for (int q = 0; q < 4; ++q) {
          const h2 wv = wb[l + q*64];
#pragma unroll
          for (int tw = 0; tw < 8; ++tw)
#pragma unroll
            for (int b = 0; b < 2; ++b)
              ca[tw][b] = fdot2f(wv, ((const h2*)&hW[tw][b][0])[l + q*64], ca[tw][b]);
        }
#pragma unroll
        for (int tw = 0; tw < 8; ++tw) {
          const int t = d ? 1023 - (s8*8 + tw) : (s8*8 + tw);
#pragma unroll
          for (int b = 0; b < 2; ++b) {
            float cs = ca[tw][b];
            for (int off = 1; off < 64; off <<= 1) cs += __shfl_xor(cs, off);
            if (l == 0) atomAddF(&cp[(b0+b)*1024 + t], cs);
          }
        }
      }
      __syncthreads();   // hW/xW stable until next window's restage
    }
  }
}

// ---------------------------------------------------------------------------
// faithful torch h.view(B,-1) projection (verified r3): K = 2048.
// ---------------------------------------------------------------------------
__global__ __launch_bounds__(256, 1)
void k_we2d(const float* __restrict__ hfin, const float* __restrict__ We2d,
            const float* __restrict__ be2d, float* __restrict__ dech,
            int* __restrict__ tok)
{
  const int g = blockIdx.x, tid = threadIdx.x;
  const int r = tid >> 2, jl = tid & 3;
  const int j = g*4 + jl;
  const float* wr = We2d + (size_t)j*2048;
  float acc = 0.f;
  for (int c = 0; c < 2048; c += 4) {
    const int q = r*4 + (c >> 9);
    acc += dot4(*(const f4*)&hfin[((q >> 6)*64 + (q & 63))*512 + (c & 511)],
                *(const f4*)&wr[c]);
  }
  acc += be2d[j];
  const int lp = r >> 5, bb2 = 2*(r & 31) + (j >> 9), hh = j & 511;
  dech[(lp*64 + bb2)*512 + hh] = acc;   // parity 0
  if (g == 0 && tid < 64) tok[tid] = 0;
}

// ---------------------------------------------------------------------------
// persistent decoder (r8-proven structure; Z/U fp16).
// ---------------------------------------------------------------------------
__global__ __launch_bounds__(256, 1)
void k_dec(const float* __restrict__ emb, const float* __restrict__ dWih,
           const float* __restrict__ dWhh, const float* __restrict__ dbih,
           const float* __restrict__ dbhh, const float* __restrict__ Wout,
           const float* __restrict__ bout, const _Float16* __restrict__ Zp,
           const _Float16* __restrict__ Up, const float* __restrict__ cp,
           float* __restrict__ dech, float* __restrict__ scor,
           float* __restrict__ pvU, float* __restrict__ pms,
           int* __restrict__ tok, int* __restrict__ flags,
           float* __restrict__ out)
{
  __shared__ float shmU[4][128];
  __shared__ float wms[8];
  __shared__ float shv[512];
  __shared__ float shl[128];

  const int g = blockIdx.x, tid = threadIdx.x;

  for (int s = 0; s < 32; ++s) {
    const int p = s & 1, pn = p ^ 1;
    const int tb = s*4;

    // ---- phase A: decoder cell, layer 0 ----
    bar_wait(flags, BC_DEC, tb);
    if (g < 64) {
      const int b = tid & 63, jj = tid >> 6;
      const int tk = aldi(tok + b);
      const float* xi = emb + (size_t)tk*512;
      const float* hh = dech + ((p*2 + 0)*64 + b)*512;
#pragma unroll
      for (int o = 0; o < 2; ++o) {
        const int j = g*8 + jj + o*4;
        const float* wi = dWih + (size_t)j*512;
        const float* wh = dWhh + (size_t)j*512;
        float acc = dbih[j] + dbhh[j];
        for (int k = 0; k < 512; k += 4) {
          acc += dot4(*(const f4*)&xi[k], *(const f4*)&wi[k]);
          acc += dot4(ald4(&hh[k]), *(const f4*)&wh[k]);
        }
        ast(&dech[((pn*2 + 0)*64 + b)*512 + j], tanhf(acc));
      }
    }
    bar_arrive(flags, CNT_DEC, BC_DEC, 256, tb+1);

    // ---- phase B: decoder cell, layer 1 ----
    bar_wait(flags, BC_DEC, tb+1);
    if (g < 64) {
      const int b = tid & 63, jj = tid >> 6;
      const float* xi = dech + ((pn*2 + 0)*64 + b)*512;
      const float* hh = dech + ((p*2 + 1)*64 + b)*512;
#pragma unroll
      for (int o = 0; o < 2; ++o) {
        const int j = g*8 + jj + o*4;
        const float* wi = dWih + (size_t)(512 + j)*512;
        const float* wh = dWhh + (size_t)(512 + j)*512;
        float acc = dbih[512 + j] + dbhh[512 + j];
        for (int k = 0; k < 512; k += 4) {
          acc += dot4(ald4(&xi[k]), *(const f4*)&wi[k]);
          acc += dot4(ald4(&hh[k]), *(const f4*)&wh[k]);
        }
        ast(&dech[((pn*2 + 1)*64 + b)*512 + j], tanhf(acc));
      }
    }
    bar_arrive(flags, CNT_DEC, BC_DEC, 256, tb+2);

    // ---- phase D: attention via Z.vec + c, accumulate U-weighted sums ----
    bar_wait(flags, BC_DEC, tb+2);
    {
      const int b = g >> 2, quarter = g & 3;
      const int w = tid >> 6, lane = tid & 63;
      const float* vecb = dech + ((pn*2 + 1)*64 + b)*512;
      float vr[8];
      *(f4*)&vr[0] = ald4(&vecb[lane*8]);
      *(f4*)&vr[4] = ald4(&vecb[lane*8 + 4]);
      float m = -INFINITY, ssum = 0.f, vu0 = 0.f, vu1 = 0.f;
      const int t0 = quarter*256 + w*64;
      for (int tg = 0; tg < 64; tg += 4) {
        float zz[4][8]; float cc[4]; float2 uu[4];
#pragma unroll
        for (int u = 0; u < 4; ++u) {
          const int t = t0 + tg + u;
          ld8(Zp + ((size_t)b*1024 + t)*512 + lane*8, zz[u]);
          h2 uh = ((const h2*)(Up + ((size_t)b*1024 + t)*128))[lane];
          uu[u].x = (float)uh.x; uu[u].y = (float)uh.y;
          cc[u] = cp[b*1024 + t];
        }
#pragma unroll
        for (int u = 0; u < 4; ++u) {
          float sc = 0.f;
#pragma unroll
          for (int z = 0; z < 8; ++z) sc += zz[u][z]*vr[z];
#pragma unroll
          for (int off = 1; off < 64; off <<= 1) sc += __shfl_xor(sc, off);
          sc += cc[u];
          if (lane == 0) ast(&scor[b*1024 + t0 + tg + u], sc);
          const float mn = fmaxf(m, sc);
          const float al = expf(m - mn);
          const float wt = expf(sc - mn);
          ssum = ssum*al + wt;
          vu0 = vu0*al + wt*uu[u].x;
          vu1 = vu1*al + wt*uu[u].y;
          m = mn;
        }
      }
      shmU[w][lane*2] = vu0; shmU[w][lane*2 + 1] = vu1;
      if (lane == 0) { wms[w] = m; wms[4 + w] = ssum; }
      __syncthreads();
      const float M = fmaxf(fmaxf(wms[0], wms[1]), fmaxf(wms[2], wms[3]));
      const float e0 = expf(wms[0]-M), e1 = expf(wms[1]-M),
                  e2 = expf(wms[2]-M), e3 = expf(wms[3]-M);
      const float S = e0*wms[4] + e1*wms[5] + e2*wms[6] + e3*wms[7];
      if (tid < 128)
        ast(&pvU[(b*4 + quarter)*128 + tid],
            e0*shmU[0][tid] + e1*shmU[1][tid] + e2*shmU[2][tid] + e3*shmU[3][tid]);
      if (tid == 0) ast2(&pms[(b*4+quarter)*2], M, S);
    }
    bar_arrive(flags, CNT_DEC, BC_DEC, 256, tb+3);

    // ---- phase E: combine, logits, argmax, outputs ----
    bar_wait(flags, BC_DEC, tb+3);
    if (g < 64) {
      const int b = g;
      f2 ms[4];
#pragma unroll
      for (int c = 0; c < 4; ++c) ms[c] = ald2(&pms[(b*4 + c)*2]);
      const float M = fmaxf(fmaxf(ms[0].x, ms[1].x), fmaxf(ms[2].x, ms[3].x));
      float ee[4]; float S = 0.f;
#pragma unroll
      for (int c = 0; c < 4; ++c) { ee[c] = expf(ms[c].x - M); S += ee[c]*ms[c].y; }
      const float invS = 1.f/S;
      const float* vecb = dech + ((pn*2 + 1)*64 + b)*512;
      {
        f2 v = ald2(&vecb[tid*2]);
        shv[tid*2] = v.x; shv[tid*2+1] = v.y;
      }
      __syncthreads();
      if (tid < 128) {
        const float* wr = Wout + (size_t)tid*1536;
        float acc = bout[tid];
        for (int k = 0; k < 512; k += 4)
          acc += dot4(*(const f4*)&shv[k], *(const f4*)&wr[k]);
        float att = 0.f;
#pragma unroll
        for (int c = 0; c < 4; ++c) att += ee[c]*ald(&pvU[(b*4 + c)*128 + tid]);
        acc += att * invS;
        shl[tid] = acc;
        out[(b*32 + s)*128 + tid] = acc;              // vec_out
      }
      __syncthreads();
      if (tid == 0) {
        float best = shl[0]; int bi = 0;
        for (int j = 1; j < 128; ++j) if (shl[j] > best) { best = shl[j]; bi = j; }
        asti(&tok[b], bi);
      }
      {
        const f4 scv = ald4(&scor[b*1024 + tid*4]);
        const int t4 = tid*4;
        out[327680 + (b*32 + s)*1024 + t4 + 0] = expf(scv.x - M)*invS;
        out[327680 + (b*32 + s)*1024 + t4 + 1] = expf(scv.y - M)*invS;
        out[327680 + (b*32 + s)*1024 + t4 + 2] = expf(scv.z - M)*invS;
        out[327680 + (b*32 + s)*1024 + t4 + 3] = expf(scv.w - M)*invS;
      }
      if (s == 31) {
        for (int u = tid; u < 1024; u += 256) {
          const int l = u >> 9, h = u & 511;
          out[262144 + (l*64 + b)*512 + h] = ald(&dech[((pn*2 + l)*64 + b)*512 + h]);
        }
      }
    }
    bar_arrive(flags, CNT_DEC, BC_DEC, 256, tb+4);
  }
}

// ---------------------------------------------------------------------------
extern "C" void kernel_launch(void* const* d_in, const int* in_sizes, int n_in,
                              void* d_out, int out_size, void* d_ws, size_t ws_size,
                              hipStream_t stream) {
  (void)in_sizes; (void)n_in;
  const float* x     = (const float*)d_in[0];
  const float* Wih0  = (const float*)d_in[1];
  const float* Whh0  = (const float*)d_in[2];
  const float* bih0  = (const float*)d_in[3];
  const float* bhh0  = (const float*)d_in[4];
  const float* Wih1  = (const float*)d_in[5];
  const float* Whh1  = (const float*)d_in[6];
  const float* bih1  = (const float*)d_in[7];
  const float* bhh1  = (const float*)d_in[8];
  const float* emb   = (const float*)d_in[9];
  const float* dWih  = (const float*)d_in[10];
  const float* dWhh  = (const float*)d_in[11];
  const float* dbih  = (const float*)d_in[12];
  const float* dbhh  = (const float*)d_in[13];
  const float* Wq    = (const float*)d_in[14];
  const float* bqv   = (const float*)d_in[15];
  const float* We2d  = (const float*)d_in[16];
  const float* be2d  = (const float*)d_in[17];
  const float* Wout  = (const float*)d_in[18];
  const float* boutv = (const float*)d_in[19];

  char* base = (char*)d_ws;
  size_t off = 0;
  auto carve = [&](size_t bytes) { size_t o = off; off += (bytes + 255) & ~(size_t)255; return o; };
  const size_t o_y0   = carve(134217728);  // [64][1024][1024] fp16
  const size_t o_Z    = carve(67108864);   // [64][1024][512] fp16   (zeroed)
  const size_t o_U    = carve(16777216);   // [64][1024][128] fp16   (zeroed)
  const size_t o_cp   = carve(262144);     // [64][1024] f32         (zeroed)
  const size_t o_flag = carve(16384);      // decoder flags          (zeroed)
  const size_t o_w0h  = carve(6291456);    // Whh0 f32 k-major pack
  const size_t o_w1h  = carve(6291456);    // Whh1 f32 k-major pack
  const size_t o_w1x  = carve(6291456);    // Wih1 fp16 pack
  const size_t o_wqp  = carve(1048576);    // Wq pack
  const size_t o_upk  = carve(262144);     // WoutA pack
  const size_t o_bqp  = carve(2048);       // bq pack
  const size_t o_hfin = carve(524288);     // [4][64][512] f32
  const size_t o_dech = carve(524288);
  const size_t o_scor = carve(262144);
  const size_t o_pvU  = carve(131072);
  const size_t o_pms  = carve(2048);
  const size_t o_tok  = carve(256);
  const size_t NEED   = off;

  if (ws_size < NEED) {  // canary: diagnosable, no fault
    hipMemsetAsync(d_out, 0, (size_t)out_size * 4, stream);
    return;
  }

  _Float16* y0   = (_Float16*)(base + o_y0);
  _Float16* Zp   = (_Float16*)(base + o_Z);
  _Float16* Up   = (_Float16*)(base + o_U);
  float*    cp   = (float*)(base + o_cp);
  int*      flags= (int*)(base + o_flag);
  float*    w0h  = (float*)(base + o_w0h);
  float*    w1h  = (float*)(base + o_w1h);
  _Float16* w1x  = (_Float16*)(base + o_w1x);
  _Float16* wqp  = (_Float16*)(base + o_wqp);
  _Float16* upk  = (_Float16*)(base + o_upk);
  _Float16* bqp  = (_Float16*)(base + o_bqp);
  float*    hfin = (float*)(base + o_hfin);
  float*    dech = (float*)(base + o_dech);
  float*    scor = (float*)(base + o_scor);
  float*    pvU  = (float*)(base + o_pvU);
  float*    pms  = (float*)(base + o_pms);
  int*      tok  = (int*)(base + o_tok);

  hipMemsetAsync(base + o_Z, 0, (o_flag + 16384) - o_Z, stream);

  k_packf<<<384, 256, 0, stream>>>(Whh0, w0h);
  k_packf<<<384, 256, 0, stream>>>(Whh1, w1h);
  k_pack<<<512, 256, 0, stream>>>(Wih1, w1x, 1536, 512, 1024, 1, 0, 1572864);
  k_pack<<<128, 256, 0, stream>>>(Wq,   wqp,  512, 256, 1, 512, 0, 262144);
  k_pack<<<64,  256, 0, stream>>>(Wout, upk,  128, 256, 1536, 1, 512, 512);
  k_pack<<<8,   256, 0, stream>>>(bqv,  bqp,  1,   256, 0, 1, 0, 512);

  k_gru<0><<<64, 512, 0, stream>>>(
      x, nullptr, y0, w0h, nullptr, Wih0, bih0, bhh0, hfin, 0,
      nullptr, nullptr, nullptr, nullptr, nullptr, nullptr);
  k_gru<1><<<64, 512, 0, stream>>>(
      nullptr, y0, nullptr, w1h, w1x, nullptr, bih1, bhh1, hfin, 2,
      wqp, upk, bqp, Zp, Up, cp);

  k_we2d<<<256, 256, 0, stream>>>(hfin, We2d, be2d, dech, tok);
  k_dec<<<256, 256, 0, stream>>>(emb, dWih, dWhh, dbih, dbhh, Wout, boutv,
                                 Zp, Up, cp, dech, scor, pvU, pms, tok,
                                 flags, (float*)d_out);
}